// Round 2
// baseline (647.518 us; speedup 1.0000x reference)
//
#include <hip/hip_runtime.h>
#include <hip/hip_bf16.h>

// MHA: B=256, T=256, E=384, H=6, D=64.  fp32 in/out, bf16 MFMA internally.
//
//   prep:  wq/wk/wv -> wt[3][H][D][E] bf16 (B^T layout), w_proj -> wpt[n][k] bf16
//   xcast: x fp32 -> xb bf16
//   qkv:   one GEMM per (m-tile, head): B-tile = [wq|wk|wv] (192 rows).
//          Q,K -> [B][H][T][D]; V -> Vt[B][H][D][T] straight from the epilogue
//          (lane holds 4 consecutive t for fixed d => packed ushort4 stores).
//          Register double-buffered: next K-tile's global loads issued under
//          the current tile's MFMA phase. __launch_bounds__(256,2) raises the
//          VGPR budget to 256 so the ~200 live regs (96 acc + 48 prefetch +
//          frags) do NOT spill (round-1 lesson: default target spilled ->
//          +700 MB scratch writes).
//   attn:  flash-style: per kt-tile S=QK^T -> exp (no max-sub) -> P via LDS -> O += P·V
//          K/V tile for kt+1 prefetched to regs during compute of kt.
//   proj:  out = attout @ w_proj + b_proj (128x128 tile), same reg double-buffer,
//          same (256,2) bound.

#define Bn 256
#define Tn 256
#define En 384
#define Hn 6
#define Dn 64

typedef __bf16 bf16x8 __attribute__((ext_vector_type(8)));
typedef float f32x4 __attribute__((ext_vector_type(4)));
typedef unsigned short u16x8 __attribute__((ext_vector_type(8)));

static __device__ __forceinline__ unsigned short f2bf(float f) {
    unsigned int u = __builtin_bit_cast(unsigned int, f);
    u += 0x7fffu + ((u >> 16) & 1u);   // RNE
    return (unsigned short)(u >> 16);
}

static __device__ __forceinline__ f32x4 mfma16(bf16x8 a, bf16x8 b, f32x4 c) {
    return __builtin_amdgcn_mfma_f32_16x16x32_bf16(a, b, c, 0, 0, 0);
}

// ---------------------------------------------------------------- prep
__global__ __launch_bounds__(256) void prep_kernel(
    const float* __restrict__ wq, const float* __restrict__ wk,
    const float* __restrict__ wv, const float* __restrict__ wp,
    unsigned short* __restrict__ wt, unsigned short* __restrict__ wpt) {
    const int NW = 3 * Hn * Dn * En;      // 442368
    const int NP = En * En;               // 147456
    int idx = blockIdx.x * 256 + threadIdx.x;
    if (idx < NW) {
        int e = idx % En;
        int d = (idx / En) % Dn;
        int h = (idx / (En * Dn)) % Hn;
        int t = idx / (En * Dn * Hn);
        const float* src = (t == 0) ? wq : (t == 1) ? wk : wv;
        wt[idx] = f2bf(src[(h * En + e) * Dn + d]);
    } else if (idx < NW + NP) {
        int j = idx - NW;
        int k = j % En;
        int n = j / En;
        wpt[j] = f2bf(wp[k * En + n]);
    }
}

// ---------------------------------------------------------------- x -> bf16
__global__ __launch_bounds__(256) void xcast_kernel(
    const float* __restrict__ x, unsigned short* __restrict__ xb) {
    size_t i = ((size_t)blockIdx.x * 256 + threadIdx.x) * 8;
    float4 f0 = *(const float4*)(x + i);
    float4 f1 = *(const float4*)(x + i + 4);
    u16x8 p;
    p[0] = f2bf(f0.x); p[1] = f2bf(f0.y); p[2] = f2bf(f0.z); p[3] = f2bf(f0.w);
    p[4] = f2bf(f1.x); p[5] = f2bf(f1.y); p[6] = f2bf(f1.z); p[7] = f2bf(f1.w);
    *(u16x8*)(xb + i) = p;
}

// ---------------------------------------------------------------- QKV projection (merged)
// grid (512, 6): m-tile(128 rows of B*T) x head. Tile 128x192, 4 waves in 2x2,
// each wave 64x96 (acc[4][6]). B-tile rows: n in [0,192): tensor=n>>6, d=n&63.
__global__ __launch_bounds__(256, 2) void qkv_gemm(
    const unsigned short* __restrict__ xb, const unsigned short* __restrict__ wt,
    unsigned short* __restrict__ Qo, unsigned short* __restrict__ Ko,
    unsigned short* __restrict__ Vt) {
    __shared__ unsigned short As[128][72];
    __shared__ unsigned short Bs[192][72];

    const int m0 = blockIdx.x * 128;
    const int h = blockIdx.y;

    const int tid = threadIdx.x;
    const int wave = tid >> 6, lane = tid & 63;
    const int quad = lane >> 4, l16 = lane & 15;
    const int mw = (wave >> 1) * 64, nw = (wave & 1) * 96;

    f32x4 acc[4][6];
#pragma unroll
    for (int i = 0; i < 4; ++i)
#pragma unroll
        for (int j = 0; j < 6; ++j) acc[i][j] = (f32x4){0.f, 0.f, 0.f, 0.f};

    const int ar = tid >> 1, ac0 = (tid & 1) * 32;   // A: 2 threads/row, 32 bf16 each
    // B row tid (<192): tensor = tid>>6, d = tid&63
    const unsigned short* wrow = wt + (size_t)(((tid >> 6) * Hn + h) * Dn + (tid & 63)) * En;
    const unsigned short* xrow = xb + (size_t)(m0 + ar) * En + ac0;

    // prologue: load K-tile 0 into registers
    uint4 ra[4];
    uint4 rb[8];
#pragma unroll
    for (int i = 0; i < 4; ++i) ra[i] = *(const uint4*)(xrow + i * 8);
    if (tid < 192) {
#pragma unroll
        for (int i = 0; i < 8; ++i) rb[i] = *(const uint4*)(wrow + i * 8);
    }

    for (int kb = 0; kb < 6; ++kb) {
        // stage current tile (vmcnt wait happens here, after a full compute phase)
#pragma unroll
        for (int i = 0; i < 4; ++i) *(uint4*)&As[ar][ac0 + i * 8] = ra[i];
        if (tid < 192) {
#pragma unroll
            for (int i = 0; i < 8; ++i) *(uint4*)&Bs[tid][i * 8] = rb[i];
        }
        __syncthreads();

        // issue next tile's global loads: in flight during the MFMA phase below
        if (kb < 5) {
            const int k0 = (kb + 1) * 64;
            const unsigned short* xr = xrow + k0;
#pragma unroll
            for (int i = 0; i < 4; ++i) ra[i] = *(const uint4*)(xr + i * 8);
            if (tid < 192) {
                const unsigned short* wr = wrow + k0;
#pragma unroll
                for (int i = 0; i < 8; ++i) rb[i] = *(const uint4*)(wr + i * 8);
            }
        }

#pragma unroll
        for (int ks = 0; ks < 2; ++ks) {
            bf16x8 a[4], b[6];
#pragma unroll
            for (int mi = 0; mi < 4; ++mi)
                a[mi] = *(const bf16x8*)&As[mw + mi * 16 + l16][ks * 32 + quad * 8];
#pragma unroll
            for (int ni = 0; ni < 6; ++ni)
                b[ni] = *(const bf16x8*)&Bs[nw + ni * 16 + l16][ks * 32 + quad * 8];
#pragma unroll
            for (int mi = 0; mi < 4; ++mi)
#pragma unroll
                for (int ni = 0; ni < 6; ++ni) acc[mi][ni] = mfma16(a[mi], b[ni], acc[mi][ni]);
        }
        __syncthreads();
    }

    // epilogue: per ni, tensor = (nw+ni*16)>>6 is wave-uniform
    const int b = m0 >> 8, tbase = m0 & 255;
    unsigned short* qkbase[2] = {
        Qo + (size_t)((b * Hn + h) * Tn) * Dn,
        Ko + (size_t)((b * Hn + h) * Tn) * Dn };
    unsigned short* vdst = Vt + (size_t)((b * Hn + h) * Dn) * Tn;
#pragma unroll
    for (int ni = 0; ni < 6; ++ni) {
        const int ng = nw + ni * 16;
        const int tensor = ng >> 6;
        const int d = (ng & 63) + l16;
        if (tensor < 2) {
            unsigned short* dst = qkbase[tensor];
#pragma unroll
            for (int mi = 0; mi < 4; ++mi)
#pragma unroll
                for (int r = 0; r < 4; ++r) {
                    int t = tbase + mw + mi * 16 + quad * 4 + r;
                    dst[t * Dn + d] = f2bf(acc[mi][ni][r]);
                }
        } else {
#pragma unroll
            for (int mi = 0; mi < 4; ++mi) {
                int t0 = tbase + mw + mi * 16 + quad * 4;
                ushort4 pk;
                pk.x = f2bf(acc[mi][ni][0]);
                pk.y = f2bf(acc[mi][ni][1]);
                pk.z = f2bf(acc[mi][ni][2]);
                pk.w = f2bf(acc[mi][ni][3]);
                *(ushort4*)&vdst[d * Tn + t0] = pk;
            }
        }
    }
}

// ---------------------------------------------------------------- attention (flash-style)
// grid (4, H, B). 4 waves; wave w owns q rows [q0+w*16, q0+w*16+16).
// K/V tile for kt+1 prefetched to registers during compute of kt.
// Reg footprint ~100 -> no launch_bounds min-occ arg needed (no spill risk).
__global__ __launch_bounds__(256) void attn_kernel(
    const unsigned short* __restrict__ Q, const unsigned short* __restrict__ K,
    const unsigned short* __restrict__ Vt, unsigned short* __restrict__ attout) {
    __shared__ unsigned short Kt[64][72];
    __shared__ unsigned short Vl[64][72];
    __shared__ unsigned short P[64][72];

    const int qt = blockIdx.x, h = blockIdx.y, b = blockIdx.z;
    const int q0 = qt * 64;
    const unsigned short* Qb = Q + (size_t)((b * Hn + h) * Tn) * Dn;
    const unsigned short* Kb = K + (size_t)((b * Hn + h) * Tn) * Dn;
    const unsigned short* Vb = Vt + (size_t)((b * Hn + h) * Dn) * Tn;

    const int tid = threadIdx.x;
    const int wave = tid >> 6, lane = tid & 63;
    const int quad = lane >> 4, l16 = lane & 15;

    bf16x8 aq[2];
#pragma unroll
    for (int ks = 0; ks < 2; ++ks)
        aq[ks] = *(const bf16x8*)&Qb[(q0 + wave * 16 + l16) * Dn + ks * 32 + quad * 8];

    f32x4 O[4];
#pragma unroll
    for (int i = 0; i < 4; ++i) O[i] = (f32x4){0.f, 0.f, 0.f, 0.f};
    float rsum[4] = {0.f, 0.f, 0.f, 0.f};

    const int sr = tid >> 2, sc = (tid & 3) * 16;
    const int qrow_base = q0 + wave * 16 + quad * 4;
    const float cexp = 0.125f * 1.44269504f;   // scale * log2(e)

    // prologue: load kt=0 K/V tile into registers
    const unsigned short* kr0 = Kb + sr * Dn + sc;
    uint4 rk0 = *(const uint4*)kr0;
    uint4 rk1 = *(const uint4*)(kr0 + 8);
    const unsigned short* vr0 = Vb + sr * Tn + sc;
    uint4 rv0 = *(const uint4*)vr0;
    uint4 rv1 = *(const uint4*)(vr0 + 8);

    for (int kt = 0; kt <= qt; ++kt) {
        __syncthreads();           // prev iter's Kt/Vl reads done
        *(uint4*)&Kt[sr][sc]     = rk0;
        *(uint4*)&Kt[sr][sc + 8] = rk1;
        *(uint4*)&Vl[sr][sc]     = rv0;
        *(uint4*)&Vl[sr][sc + 8] = rv1;
        __syncthreads();

        // prefetch kt+1 tile: in flight under QK^T + softmax + PV below
        if (kt < qt) {
            const unsigned short* kr = Kb + ((kt + 1) * 64 + sr) * Dn + sc;
            rk0 = *(const uint4*)kr;
            rk1 = *(const uint4*)(kr + 8);
            const unsigned short* vr = Vb + sr * Tn + (kt + 1) * 64 + sc;
            rv0 = *(const uint4*)vr;
            rv1 = *(const uint4*)(vr + 8);
        }

        f32x4 S[4];
#pragma unroll
        for (int i = 0; i < 4; ++i) S[i] = (f32x4){0.f, 0.f, 0.f, 0.f};
#pragma unroll
        for (int ks = 0; ks < 2; ++ks)
#pragma unroll
            for (int ni = 0; ni < 4; ++ni) {
                bf16x8 bk = *(const bf16x8*)&Kt[ni * 16 + l16][ks * 32 + quad * 8];
                S[ni] = mfma16(aq[ks], bk, S[ni]);
            }

        // exp + row-sum + P (wave-local rows => no barrier before re-read)
#pragma unroll
        for (int ni = 0; ni < 4; ++ni)
#pragma unroll
            for (int r = 0; r < 4; ++r) {
                int col = kt * 64 + ni * 16 + l16;
                float p = exp2f(S[ni][r] * cexp);
                p = (col > qrow_base + r) ? 0.f : p;
                rsum[r] += p;
                P[wave * 16 + quad * 4 + r][ni * 16 + l16] = f2bf(p);
            }

#pragma unroll
        for (int ks = 0; ks < 2; ++ks) {
            bf16x8 ap = *(const bf16x8*)&P[wave * 16 + l16][ks * 32 + quad * 8];
#pragma unroll
            for (int ni = 0; ni < 4; ++ni) {
                bf16x8 bv = *(const bf16x8*)&Vl[ni * 16 + l16][ks * 32 + quad * 8];
                O[ni] = mfma16(ap, bv, O[ni]);
            }
        }
    }

    // reduce row sums across the 16 lanes holding each row
#pragma unroll
    for (int r = 0; r < 4; ++r) {
        float s = rsum[r];
        s += __shfl_xor(s, 1);
        s += __shfl_xor(s, 2);
        s += __shfl_xor(s, 4);
        s += __shfl_xor(s, 8);
        rsum[r] = s;
    }

    // stage O tile in LDS (reuse Kt), then coalesced 16B stores
    __syncthreads();
#pragma unroll
    for (int r = 0; r < 4; ++r) {
        float inv = 1.0f / rsum[r];
#pragma unroll
        for (int ni = 0; ni < 4; ++ni)
            Kt[wave * 16 + quad * 4 + r][ni * 16 + l16] = f2bf(O[ni][r] * inv);
    }
    __syncthreads();
    const int row = tid >> 2;          // 0..63
    const int col = (tid & 3) * 16;    // 0,16,32,48
    unsigned short* dst = attout + (size_t)(b * Tn + q0 + row) * (Hn * Dn) + h * Dn + col;
    *(uint4*)dst = *(const uint4*)&Kt[row][col];
    *(uint4*)(dst + 8) = *(const uint4*)&Kt[row][col + 8];
}

// ---------------------------------------------------------------- output projection
// grid (512, 3): 128x128 tile, register double-buffered, (256,2) so the
// ~190 live regs (64 acc + 32 prefetch + frags) do not spill.
__global__ __launch_bounds__(256, 2) void proj_gemm(
    const unsigned short* __restrict__ attout, const unsigned short* __restrict__ wpt,
    const float* __restrict__ bproj, float* __restrict__ out) {
    __shared__ unsigned short As[128][72];
    __shared__ unsigned short Bs[128][72];

    const int m0 = blockIdx.x * 128;
    const int n0 = blockIdx.y * 128;

    const int tid = threadIdx.x;
    const int wave = tid >> 6, lane = tid & 63;
    const int quad = lane >> 4, l16 = lane & 15;
    const int mw = (wave >> 1) * 64, nw = (wave & 1) * 64;

    f32x4 acc[4][4];
#pragma unroll
    for (int i = 0; i < 4; ++i)
#pragma unroll
        for (int j = 0; j < 4; ++j) acc[i][j] = (f32x4){0.f, 0.f, 0.f, 0.f};

    const int ar = tid >> 1, ac0 = (tid & 1) * 32;
    const unsigned short* arow = attout + (size_t)(m0 + ar) * En + ac0;
    const unsigned short* brow = wpt + (size_t)(n0 + ar) * En + ac0;

    uint4 ra[4], rw[4];
#pragma unroll
    for (int i = 0; i < 4; ++i) ra[i] = *(const uint4*)(arow + i * 8);
#pragma unroll
    for (int i = 0; i < 4; ++i) rw[i] = *(const uint4*)(brow + i * 8);

    for (int kb = 0; kb < 6; ++kb) {
#pragma unroll
        for (int i = 0; i < 4; ++i) *(uint4*)&As[ar][ac0 + i * 8] = ra[i];
#pragma unroll
        for (int i = 0; i < 4; ++i) *(uint4*)&Bs[ar][ac0 + i * 8] = rw[i];
        __syncthreads();

        if (kb < 5) {
            const int k0 = (kb + 1) * 64;
#pragma unroll
            for (int i = 0; i < 4; ++i) ra[i] = *(const uint4*)(arow + k0 + i * 8);
#pragma unroll
            for (int i = 0; i < 4; ++i) rw[i] = *(const uint4*)(brow + k0 + i * 8);
        }

#pragma unroll
        for (int ks = 0; ks < 2; ++ks) {
            bf16x8 a[4], bb[4];
#pragma unroll
            for (int mi = 0; mi < 4; ++mi)
                a[mi] = *(const bf16x8*)&As[mw + mi * 16 + l16][ks * 32 + quad * 8];
#pragma unroll
            for (int ni = 0; ni < 4; ++ni)
                bb[ni] = *(const bf16x8*)&Bs[nw + ni * 16 + l16][ks * 32 + quad * 8];
#pragma unroll
            for (int mi = 0; mi < 4; ++mi)
#pragma unroll
                for (int ni = 0; ni < 4; ++ni) acc[mi][ni] = mfma16(a[mi], bb[ni], acc[mi][ni]);
        }
        __syncthreads();
    }
#pragma unroll
    for (int mi = 0; mi < 4; ++mi)
#pragma unroll
        for (int ni = 0; ni < 4; ++ni)
#pragma unroll
            for (int r = 0; r < 4; ++r) {
                int row = m0 + mw + mi * 16 + quad * 4 + r;
                int col = n0 + nw + ni * 16 + l16;
                out[(size_t)row * En + col] = acc[mi][ni][r] + bproj[col];
            }
}

// ---------------------------------------------------------------- launch
extern "C" void kernel_launch(void* const* d_in, const int* in_sizes, int n_in,
                              void* d_out, int out_size, void* d_ws, size_t ws_size,
                              hipStream_t stream) {
    const float* x  = (const float*)d_in[0];
    const float* wq = (const float*)d_in[1];
    const float* wk = (const float*)d_in[2];
    const float* wv = (const float*)d_in[3];
    const float* wp = (const float*)d_in[4];
    const float* bp = (const float*)d_in[5];
    float* out = (float*)d_out;

    char* ws = (char*)d_ws;
    const size_t WT_OFF  = 0;                                  // 884736
    const size_t WPT_OFF = WT_OFF + 884736;                    // 294912
    const size_t Q_OFF   = WPT_OFF + 294912;                   // 50331648 each below
    const size_t K_OFF   = Q_OFF + 50331648ull;
    const size_t VT_OFF  = K_OFF + 50331648ull;
    const size_t XB_OFF  = VT_OFF + 50331648ull;               // xb; attout aliases this

    unsigned short* wt   = (unsigned short*)(ws + WT_OFF);
    unsigned short* wpt  = (unsigned short*)(ws + WPT_OFF);
    unsigned short* Qd   = (unsigned short*)(ws + Q_OFF);
    unsigned short* Kd   = (unsigned short*)(ws + K_OFF);
    unsigned short* Vtd  = (unsigned short*)(ws + VT_OFF);
    unsigned short* xbd  = (unsigned short*)(ws + XB_OFF);
    unsigned short* ao   = xbd;   // xb dead after qkv_gemm; attn overwrites it

    prep_kernel<<<2304, 256, 0, stream>>>(wq, wk, wv, wp, wt, wpt);
    xcast_kernel<<<12288, 256, 0, stream>>>(x, xbd);
    qkv_gemm<<<dim3(512, Hn), 256, 0, stream>>>(xbd, wt, Qd, Kd, Vtd);
    attn_kernel<<<dim3(4, Hn, Bn), 256, 0, stream>>>(Qd, Kd, Vtd, ao);
    proj_gemm<<<dim3(512, 3), 256, 0, stream>>>(ao, wpt, bp, out);
}

// Round 3
// 387.270 us; speedup vs baseline: 1.6720x; 1.6720x over previous
//
#include <hip/hip_runtime.h>
#include <hip/hip_bf16.h>

// MHA: B=256, T=256, E=384, H=6, D=64.  fp32 in/out, bf16 MFMA internally.
//
//   prep:  wq/wk/wv -> wt[3][H][D][E] bf16 (B^T layout), w_proj -> wpt[n][k] bf16
//   xcast: x fp32 -> xb bf16
//   qkv:   one GEMM per (head, m-tile): B-tile = [wq|wk|wv] (192 rows).
//          global_load_lds (16B) -> double-buffered LDS, XOR-swizzled
//          (linear dest + pre-swizzled global source + swizzled ds_read).
//          One __syncthreads per K-step: STAGE(next) in flight under MFMA.
//          Round-1/2 lesson: reg-staged prefetch spills to scratch (+720 MB
//          writes) no matter the launch_bounds; gl_lds has zero VGPR cost.
//   attn:  flash-style (round-0 structure): S=QK^T -> exp -> P via LDS -> O += P.V
//   proj:  out = attout @ w_proj + b_proj, same gl_lds 2-phase structure.

#define Bn 256
#define Tn 256
#define En 384
#define Hn 6
#define Dn 64

typedef __bf16 bf16x8 __attribute__((ext_vector_type(8)));
typedef float f32x4 __attribute__((ext_vector_type(4)));
typedef unsigned short u16x8 __attribute__((ext_vector_type(8)));

static __device__ __forceinline__ unsigned short f2bf(float f) {
    unsigned int u = __builtin_bit_cast(unsigned int, f);
    u += 0x7fffu + ((u >> 16) & 1u);   // RNE
    return (unsigned short)(u >> 16);
}

static __device__ __forceinline__ f32x4 mfma16(bf16x8 a, bf16x8 b, f32x4 c) {
    return __builtin_amdgcn_mfma_f32_16x16x32_bf16(a, b, c, 0, 0, 0);
}

// async global->LDS, 16 B per lane. LDS dest = wave-uniform base + lane*16.
static __device__ __forceinline__ void glds16(const unsigned short* g, unsigned short* l) {
    __builtin_amdgcn_global_load_lds(
        (const __attribute__((address_space(1))) unsigned int*)g,
        (__attribute__((address_space(3))) unsigned int*)l, 16, 0, 0);
}

// ---------------------------------------------------------------- prep
__global__ __launch_bounds__(256) void prep_kernel(
    const float* __restrict__ wq, const float* __restrict__ wk,
    const float* __restrict__ wv, const float* __restrict__ wp,
    unsigned short* __restrict__ wt, unsigned short* __restrict__ wpt) {
    const int NW = 3 * Hn * Dn * En;      // 442368
    const int NP = En * En;               // 147456
    int idx = blockIdx.x * 256 + threadIdx.x;
    if (idx < NW) {
        int e = idx % En;
        int d = (idx / En) % Dn;
        int h = (idx / (En * Dn)) % Hn;
        int t = idx / (En * Dn * Hn);
        const float* src = (t == 0) ? wq : (t == 1) ? wk : wv;
        wt[idx] = f2bf(src[(h * En + e) * Dn + d]);
    } else if (idx < NW + NP) {
        int j = idx - NW;
        int k = j % En;
        int n = j / En;
        wpt[j] = f2bf(wp[k * En + n]);
    }
}

// ---------------------------------------------------------------- x -> bf16
__global__ __launch_bounds__(256) void xcast_kernel(
    const float* __restrict__ x, unsigned short* __restrict__ xb) {
    size_t i = ((size_t)blockIdx.x * 256 + threadIdx.x) * 8;
    float4 f0 = *(const float4*)(x + i);
    float4 f1 = *(const float4*)(x + i + 4);
    u16x8 p;
    p[0] = f2bf(f0.x); p[1] = f2bf(f0.y); p[2] = f2bf(f0.z); p[3] = f2bf(f0.w);
    p[4] = f2bf(f1.x); p[5] = f2bf(f1.y); p[6] = f2bf(f1.z); p[7] = f2bf(f1.w);
    *(u16x8*)(xb + i) = p;
}

// ---------------------------------------------------------------- QKV projection (merged)
// grid (6, 512): head (fast, for xb L2 reuse) x m-tile(128 rows of B*T).
// Tile 128x192, 4 waves 2x2, wave 64x96 (acc[4][6]).
// LDS: double-buffered linear [.][64] tiles, XOR swizzle slot^=(row&7).
__global__ __launch_bounds__(256) void qkv_gemm(
    const unsigned short* __restrict__ xb, const unsigned short* __restrict__ wt,
    unsigned short* __restrict__ Qo, unsigned short* __restrict__ Ko,
    unsigned short* __restrict__ Vt) {
    __shared__ unsigned short As[2][128][64];   // 32 KB
    __shared__ unsigned short Bs[2][192][64];   // 48 KB  (80 KB total -> 2 blk/CU)

    const int h = blockIdx.x;
    const int m0 = blockIdx.y * 128;

    const int tid = threadIdx.x;
    const int wave = tid >> 6, lane = tid & 63;
    const int quad = lane >> 4, l16 = lane & 15;
    const int mw = (wave >> 1) * 64, nw = (wave & 1) * 96;

    f32x4 acc[4][6];
#pragma unroll
    for (int i = 0; i < 4; ++i)
#pragma unroll
        for (int j = 0; j < 6; ++j) acc[i][j] = (f32x4){0.f, 0.f, 0.f, 0.f};

    // staging geometry: chunk = 8 rows x 64 cols (1 KB = 64 lanes x 16 B).
    // lane l -> row 8k + (l>>3), physical 16B-slot l&7.
    // pre-swizzled source: logical slot j = (l&7) ^ (l>>3)  (row&7 == l>>3).
    const int lr = lane >> 3;
    const int js = (lane & 7) ^ lr;

    // A: 4 chunks/wave, rows wave*32 + i*8 + lr
    const unsigned short* ga[4];
#pragma unroll
    for (int i = 0; i < 4; ++i)
        ga[i] = xb + (size_t)(m0 + wave * 32 + i * 8 + lr) * En + js * 8;
    // B: 6 chunks/wave, n = wave*48 + i*8 + lr; row n of [wq|wk|wv] pack
    const unsigned short* gb[6];
#pragma unroll
    for (int i = 0; i < 6; ++i) {
        int n = wave * 48 + i * 8 + lr;
        gb[i] = wt + (size_t)(((n >> 6) * Hn + h) * Dn + (n & 63)) * En + js * 8;
    }

#define QKV_STAGE(buf, koff)                                              \
    do {                                                                  \
        _Pragma("unroll") for (int i = 0; i < 4; ++i)                     \
            glds16(ga[i] + (koff), &As[buf][wave * 32 + i * 8][0]);       \
        _Pragma("unroll") for (int i = 0; i < 6; ++i)                     \
            glds16(gb[i] + (koff), &Bs[buf][wave * 48 + i * 8][0]);       \
    } while (0)

    QKV_STAGE(0, 0);
    __syncthreads();                 // vmcnt(0) drain: buf0 ready

    int cur = 0;
    for (int kb = 0; kb < 6; ++kb) {
        if (kb < 5) QKV_STAGE(cur ^ 1, (kb + 1) * 64);   // DMA under MFMA below

#pragma unroll
        for (int ks = 0; ks < 2; ++ks) {
            bf16x8 a[4], b[6];
            const int ps = ((ks * 4 + quad) ^ (l16 & 7)) * 8;  // swizzled slot
#pragma unroll
            for (int mi = 0; mi < 4; ++mi)
                a[mi] = *(const bf16x8*)&As[cur][mw + mi * 16 + l16][ps];
#pragma unroll
            for (int ni = 0; ni < 6; ++ni)
                b[ni] = *(const bf16x8*)&Bs[cur][nw + ni * 16 + l16][ps];
#pragma unroll
            for (int mi = 0; mi < 4; ++mi)
#pragma unroll
                for (int ni = 0; ni < 6; ++ni) acc[mi][ni] = mfma16(a[mi], b[ni], acc[mi][ni]);
        }
        if (kb < 5) {
            __syncthreads();         // drains next-tile DMA + guards buffer swap
            cur ^= 1;
        }
    }
#undef QKV_STAGE

    // epilogue: per ni, tensor = (nw+ni*16)>>6 is wave-uniform
    const int b = m0 >> 8, tbase = m0 & 255;
    unsigned short* qkbase[2] = {
        Qo + (size_t)((b * Hn + h) * Tn) * Dn,
        Ko + (size_t)((b * Hn + h) * Tn) * Dn };
    unsigned short* vdst = Vt + (size_t)((b * Hn + h) * Dn) * Tn;
#pragma unroll
    for (int ni = 0; ni < 6; ++ni) {
        const int ng = nw + ni * 16;
        const int tensor = ng >> 6;
        const int d = (ng & 63) + l16;
        if (tensor < 2) {
            unsigned short* dst = qkbase[tensor];
#pragma unroll
            for (int mi = 0; mi < 4; ++mi)
#pragma unroll
                for (int r = 0; r < 4; ++r) {
                    int t = tbase + mw + mi * 16 + quad * 4 + r;
                    dst[t * Dn + d] = f2bf(acc[mi][ni][r]);
                }
        } else {
#pragma unroll
            for (int mi = 0; mi < 4; ++mi) {
                int t0 = tbase + mw + mi * 16 + quad * 4;
                ushort4 pk;
                pk.x = f2bf(acc[mi][ni][0]);
                pk.y = f2bf(acc[mi][ni][1]);
                pk.z = f2bf(acc[mi][ni][2]);
                pk.w = f2bf(acc[mi][ni][3]);
                *(ushort4*)&vdst[d * Tn + t0] = pk;
            }
        }
    }
}

// ---------------------------------------------------------------- attention (flash-style)
// grid (4, H, B). 4 waves; wave w owns q rows [q0+w*16, q0+w*16+16).  (round-0 version)
__global__ __launch_bounds__(256) void attn_kernel(
    const unsigned short* __restrict__ Q, const unsigned short* __restrict__ K,
    const unsigned short* __restrict__ Vt, unsigned short* __restrict__ attout) {
    __shared__ unsigned short Kt[64][72];
    __shared__ unsigned short Vl[64][72];
    __shared__ unsigned short P[64][72];

    const int qt = blockIdx.x, h = blockIdx.y, b = blockIdx.z;
    const int q0 = qt * 64;
    const unsigned short* Qb = Q + (size_t)((b * Hn + h) * Tn) * Dn;
    const unsigned short* Kb = K + (size_t)((b * Hn + h) * Tn) * Dn;
    const unsigned short* Vb = Vt + (size_t)((b * Hn + h) * Dn) * Tn;

    const int tid = threadIdx.x;
    const int wave = tid >> 6, lane = tid & 63;
    const int quad = lane >> 4, l16 = lane & 15;

    bf16x8 aq[2];
#pragma unroll
    for (int ks = 0; ks < 2; ++ks)
        aq[ks] = *(const bf16x8*)&Qb[(q0 + wave * 16 + l16) * Dn + ks * 32 + quad * 8];

    f32x4 O[4];
#pragma unroll
    for (int i = 0; i < 4; ++i) O[i] = (f32x4){0.f, 0.f, 0.f, 0.f};
    float rsum[4] = {0.f, 0.f, 0.f, 0.f};

    const int sr = tid >> 2, sc = (tid & 3) * 16;
    const int qrow_base = q0 + wave * 16 + quad * 4;
    const float cexp = 0.125f * 1.44269504f;   // scale * log2(e)

#pragma unroll
    for (int kt = 0; kt < 4; ++kt) {
        if (kt <= qt) {            // block-uniform
            __syncthreads();
            const unsigned short* kr = Kb + (kt * 64 + sr) * Dn + sc;
            *(uint4*)&Kt[sr][sc] = *(const uint4*)kr;
            *(uint4*)&Kt[sr][sc + 8] = *(const uint4*)(kr + 8);
            const unsigned short* vr = Vb + sr * Tn + kt * 64 + sc;
            *(uint4*)&Vl[sr][sc] = *(const uint4*)vr;
            *(uint4*)&Vl[sr][sc + 8] = *(const uint4*)(vr + 8);
            __syncthreads();

            f32x4 S[4];
#pragma unroll
            for (int i = 0; i < 4; ++i) S[i] = (f32x4){0.f, 0.f, 0.f, 0.f};
#pragma unroll
            for (int ks = 0; ks < 2; ++ks)
#pragma unroll
                for (int ni = 0; ni < 4; ++ni) {
                    bf16x8 bk = *(const bf16x8*)&Kt[ni * 16 + l16][ks * 32 + quad * 8];
                    S[ni] = mfma16(aq[ks], bk, S[ni]);
                }

            // exp + row-sum + P (wave-local rows => no barrier before re-read)
#pragma unroll
            for (int ni = 0; ni < 4; ++ni)
#pragma unroll
                for (int r = 0; r < 4; ++r) {
                    int col = kt * 64 + ni * 16 + l16;
                    float p = exp2f(S[ni][r] * cexp);
                    p = (col > qrow_base + r) ? 0.f : p;
                    rsum[r] += p;
                    P[wave * 16 + quad * 4 + r][ni * 16 + l16] = f2bf(p);
                }

#pragma unroll
            for (int ks = 0; ks < 2; ++ks) {
                bf16x8 ap = *(const bf16x8*)&P[wave * 16 + l16][ks * 32 + quad * 8];
#pragma unroll
                for (int ni = 0; ni < 4; ++ni) {
                    bf16x8 bv = *(const bf16x8*)&Vl[ni * 16 + l16][ks * 32 + quad * 8];
                    O[ni] = mfma16(ap, bv, O[ni]);
                }
            }
        }
    }

    // reduce row sums across the 16 lanes holding each row
#pragma unroll
    for (int r = 0; r < 4; ++r) {
        float s = rsum[r];
        s += __shfl_xor(s, 1);
        s += __shfl_xor(s, 2);
        s += __shfl_xor(s, 4);
        s += __shfl_xor(s, 8);
        rsum[r] = s;
    }

    // stage O tile in LDS (reuse Kt), then coalesced 16B stores
    __syncthreads();
#pragma unroll
    for (int r = 0; r < 4; ++r) {
        float inv = 1.0f / rsum[r];
#pragma unroll
        for (int ni = 0; ni < 4; ++ni)
            Kt[wave * 16 + quad * 4 + r][ni * 16 + l16] = f2bf(O[ni][r] * inv);
    }
    __syncthreads();
    const int row = tid >> 2;          // 0..63
    const int col = (tid & 3) * 16;    // 0,16,32,48
    unsigned short* dst = attout + (size_t)(b * Tn + q0 + row) * (Hn * Dn) + h * Dn + col;
    *(uint4*)dst = *(const uint4*)&Kt[row][col];
    *(uint4*)(dst + 8) = *(const uint4*)&Kt[row][col + 8];
}

// ---------------------------------------------------------------- output projection
// grid (3, 512): n-tile (fast, for attout L2 reuse) x m-tile. 128x128 tile,
// gl_lds double-buffered 2-phase, same swizzle as qkv.
__global__ __launch_bounds__(256) void proj_gemm(
    const unsigned short* __restrict__ attout, const unsigned short* __restrict__ wpt,
    const float* __restrict__ bproj, float* __restrict__ out) {
    __shared__ unsigned short As[2][128][64];   // 32 KB
    __shared__ unsigned short Bs[2][128][64];   // 32 KB (64 KB total -> 2 blk/CU)

    const int n0 = blockIdx.x * 128;
    const int m0 = blockIdx.y * 128;

    const int tid = threadIdx.x;
    const int wave = tid >> 6, lane = tid & 63;
    const int quad = lane >> 4, l16 = lane & 15;
    const int mw = (wave >> 1) * 64, nw = (wave & 1) * 64;

    f32x4 acc[4][4];
#pragma unroll
    for (int i = 0; i < 4; ++i)
#pragma unroll
        for (int j = 0; j < 4; ++j) acc[i][j] = (f32x4){0.f, 0.f, 0.f, 0.f};

    const int lr = lane >> 3;
    const int js = (lane & 7) ^ lr;

    const unsigned short* ga[4];
    const unsigned short* gb[4];
#pragma unroll
    for (int i = 0; i < 4; ++i) {
        ga[i] = attout + (size_t)(m0 + wave * 32 + i * 8 + lr) * En + js * 8;
        gb[i] = wpt + (size_t)(n0 + wave * 32 + i * 8 + lr) * En + js * 8;
    }

#define PROJ_STAGE(buf, koff)                                             \
    do {                                                                  \
        _Pragma("unroll") for (int i = 0; i < 4; ++i)                     \
            glds16(ga[i] + (koff), &As[buf][wave * 32 + i * 8][0]);       \
        _Pragma("unroll") for (int i = 0; i < 4; ++i)                     \
            glds16(gb[i] + (koff), &Bs[buf][wave * 32 + i * 8][0]);       \
    } while (0)

    PROJ_STAGE(0, 0);
    __syncthreads();

    int cur = 0;
    for (int kb = 0; kb < 6; ++kb) {
        if (kb < 5) PROJ_STAGE(cur ^ 1, (kb + 1) * 64);

#pragma unroll
        for (int ks = 0; ks < 2; ++ks) {
            bf16x8 a[4], bb[4];
            const int ps = ((ks * 4 + quad) ^ (l16 & 7)) * 8;
#pragma unroll
            for (int mi = 0; mi < 4; ++mi)
                a[mi] = *(const bf16x8*)&As[cur][mw + mi * 16 + l16][ps];
#pragma unroll
            for (int ni = 0; ni < 4; ++ni)
                bb[ni] = *(const bf16x8*)&Bs[cur][nw + ni * 16 + l16][ps];
#pragma unroll
            for (int mi = 0; mi < 4; ++mi)
#pragma unroll
                for (int ni = 0; ni < 4; ++ni) acc[mi][ni] = mfma16(a[mi], bb[ni], acc[mi][ni]);
        }
        if (kb < 5) {
            __syncthreads();
            cur ^= 1;
        }
    }
#undef PROJ_STAGE

#pragma unroll
    for (int mi = 0; mi < 4; ++mi)
#pragma unroll
        for (int ni = 0; ni < 4; ++ni)
#pragma unroll
            for (int r = 0; r < 4; ++r) {
                int row = m0 + mw + mi * 16 + quad * 4 + r;
                int col = n0 + nw + ni * 16 + l16;
                out[(size_t)row * En + col] = acc[mi][ni][r] + bproj[col];
            }
}

// ---------------------------------------------------------------- launch
extern "C" void kernel_launch(void* const* d_in, const int* in_sizes, int n_in,
                              void* d_out, int out_size, void* d_ws, size_t ws_size,
                              hipStream_t stream) {
    const float* x  = (const float*)d_in[0];
    const float* wq = (const float*)d_in[1];
    const float* wk = (const float*)d_in[2];
    const float* wv = (const float*)d_in[3];
    const float* wp = (const float*)d_in[4];
    const float* bp = (const float*)d_in[5];
    float* out = (float*)d_out;

    char* ws = (char*)d_ws;
    const size_t WT_OFF  = 0;                                  // 884736
    const size_t WPT_OFF = WT_OFF + 884736;                    // 294912
    const size_t Q_OFF   = WPT_OFF + 294912;                   // 50331648 each below
    const size_t K_OFF   = Q_OFF + 50331648ull;
    const size_t VT_OFF  = K_OFF + 50331648ull;
    const size_t XB_OFF  = VT_OFF + 50331648ull;               // xb; attout aliases this

    unsigned short* wt   = (unsigned short*)(ws + WT_OFF);
    unsigned short* wpt  = (unsigned short*)(ws + WPT_OFF);
    unsigned short* Qd   = (unsigned short*)(ws + Q_OFF);
    unsigned short* Kd   = (unsigned short*)(ws + K_OFF);
    unsigned short* Vtd  = (unsigned short*)(ws + VT_OFF);
    unsigned short* xbd  = (unsigned short*)(ws + XB_OFF);
    unsigned short* ao   = xbd;   // xb dead after qkv_gemm; attn overwrites it

    prep_kernel<<<2304, 256, 0, stream>>>(wq, wk, wv, wp, wt, wpt);
    xcast_kernel<<<12288, 256, 0, stream>>>(x, xbd);
    qkv_gemm<<<dim3(Hn, 512), 256, 0, stream>>>(xbd, wt, Qd, Kd, Vtd);
    attn_kernel<<<dim3(4, Hn, Bn), 256, 0, stream>>>(Qd, Kd, Vtd, ao);
    proj_gemm<<<dim3(3, 512), 256, 0, stream>>>(ao, wpt, bp, out);
}

// Round 4
// 379.416 us; speedup vs baseline: 1.7066x; 1.0207x over previous
//
#include <hip/hip_runtime.h>
#include <hip/hip_bf16.h>

// MHA: B=256, T=256, E=384, H=6, D=64.  fp32 in/out, bf16 MFMA internally.
//
//   prep:  wq/wk/wv -> wt[3][H][D][E] bf16 (B^T layout), w_proj -> wpt[n][k] bf16
//   xcast: x fp32 -> xb bf16
//   qkv:   one GEMM per (head, m-tile): B-tile = [wq|wk|wv] (192 rows).
//          global_load_lds (16B) -> double-buffered LDS, XOR-swizzled
//          (linear dest + pre-swizzled global source + swizzled ds_read).
//          One __syncthreads per K-step: STAGE(next) in flight under MFMA.
//          (round-3 verified: 0 bank conflicts, no spill, 275->104 us)
//   attn:  NEW (round 4): one block per (b,h); K[256][64] + V^T[64][256]
//          staged in LDS ONCE (XOR-swizzled glds16), then barrier-free:
//          each of 4 waves handles q-row groups {w,7-w,8+w,15-w} (exactly
//          10 kt-iters per wave -> perfect causal balance). K/V fetched
//          from HBM exactly once per (b,h).
//   proj:  out = attout @ w_proj + b_proj, gl_lds 2-phase (round-3 verified).

#define Bn 256
#define Tn 256
#define En 384
#define Hn 6
#define Dn 64

typedef __bf16 bf16x8 __attribute__((ext_vector_type(8)));
typedef float f32x4 __attribute__((ext_vector_type(4)));
typedef unsigned short u16x8 __attribute__((ext_vector_type(8)));

static __device__ __forceinline__ unsigned short f2bf(float f) {
    unsigned int u = __builtin_bit_cast(unsigned int, f);
    u += 0x7fffu + ((u >> 16) & 1u);   // RNE
    return (unsigned short)(u >> 16);
}

static __device__ __forceinline__ f32x4 mfma16(bf16x8 a, bf16x8 b, f32x4 c) {
    return __builtin_amdgcn_mfma_f32_16x16x32_bf16(a, b, c, 0, 0, 0);
}

// async global->LDS, 16 B per lane. LDS dest = wave-uniform base + lane*16.
static __device__ __forceinline__ void glds16(const unsigned short* g, unsigned short* l) {
    __builtin_amdgcn_global_load_lds(
        (const __attribute__((address_space(1))) unsigned int*)g,
        (__attribute__((address_space(3))) unsigned int*)l, 16, 0, 0);
}

// ---------------------------------------------------------------- prep
__global__ __launch_bounds__(256) void prep_kernel(
    const float* __restrict__ wq, const float* __restrict__ wk,
    const float* __restrict__ wv, const float* __restrict__ wp,
    unsigned short* __restrict__ wt, unsigned short* __restrict__ wpt) {
    const int NW = 3 * Hn * Dn * En;      // 442368
    const int NP = En * En;               // 147456
    int idx = blockIdx.x * 256 + threadIdx.x;
    if (idx < NW) {
        int e = idx % En;
        int d = (idx / En) % Dn;
        int h = (idx / (En * Dn)) % Hn;
        int t = idx / (En * Dn * Hn);
        const float* src = (t == 0) ? wq : (t == 1) ? wk : wv;
        wt[idx] = f2bf(src[(h * En + e) * Dn + d]);
    } else if (idx < NW + NP) {
        int j = idx - NW;
        int k = j % En;
        int n = j / En;
        wpt[j] = f2bf(wp[k * En + n]);
    }
}

// ---------------------------------------------------------------- x -> bf16
__global__ __launch_bounds__(256) void xcast_kernel(
    const float* __restrict__ x, unsigned short* __restrict__ xb) {
    size_t i = ((size_t)blockIdx.x * 256 + threadIdx.x) * 8;
    float4 f0 = *(const float4*)(x + i);
    float4 f1 = *(const float4*)(x + i + 4);
    u16x8 p;
    p[0] = f2bf(f0.x); p[1] = f2bf(f0.y); p[2] = f2bf(f0.z); p[3] = f2bf(f0.w);
    p[4] = f2bf(f1.x); p[5] = f2bf(f1.y); p[6] = f2bf(f1.z); p[7] = f2bf(f1.w);
    *(u16x8*)(xb + i) = p;
}

// ---------------------------------------------------------------- QKV projection (merged)
// grid (6, 512): head (fast, for xb L2 reuse) x m-tile(128 rows of B*T).
// Tile 128x192, 4 waves 2x2, wave 64x96 (acc[4][6]).
// LDS: double-buffered linear [.][64] tiles, XOR swizzle slot^=(row&7).
__global__ __launch_bounds__(256) void qkv_gemm(
    const unsigned short* __restrict__ xb, const unsigned short* __restrict__ wt,
    unsigned short* __restrict__ Qo, unsigned short* __restrict__ Ko,
    unsigned short* __restrict__ Vt) {
    __shared__ unsigned short As[2][128][64];   // 32 KB
    __shared__ unsigned short Bs[2][192][64];   // 48 KB  (80 KB total -> 2 blk/CU)

    const int h = blockIdx.x;
    const int m0 = blockIdx.y * 128;

    const int tid = threadIdx.x;
    const int wave = tid >> 6, lane = tid & 63;
    const int quad = lane >> 4, l16 = lane & 15;
    const int mw = (wave >> 1) * 64, nw = (wave & 1) * 96;

    f32x4 acc[4][6];
#pragma unroll
    for (int i = 0; i < 4; ++i)
#pragma unroll
        for (int j = 0; j < 6; ++j) acc[i][j] = (f32x4){0.f, 0.f, 0.f, 0.f};

    // staging geometry: chunk = 8 rows x 64 cols (1 KB = 64 lanes x 16 B).
    // lane l -> row 8k + (l>>3), physical 16B-slot l&7.
    // pre-swizzled source: logical slot j = (l&7) ^ (l>>3)  (row&7 == l>>3).
    const int lr = lane >> 3;
    const int js = (lane & 7) ^ lr;

    // A: 4 chunks/wave, rows wave*32 + i*8 + lr
    const unsigned short* ga[4];
#pragma unroll
    for (int i = 0; i < 4; ++i)
        ga[i] = xb + (size_t)(m0 + wave * 32 + i * 8 + lr) * En + js * 8;
    // B: 6 chunks/wave, n = wave*48 + i*8 + lr; row n of [wq|wk|wv] pack
    const unsigned short* gb[6];
#pragma unroll
    for (int i = 0; i < 6; ++i) {
        int n = wave * 48 + i * 8 + lr;
        gb[i] = wt + (size_t)(((n >> 6) * Hn + h) * Dn + (n & 63)) * En + js * 8;
    }

#define QKV_STAGE(buf, koff)                                              \
    do {                                                                  \
        _Pragma("unroll") for (int i = 0; i < 4; ++i)                     \
            glds16(ga[i] + (koff), &As[buf][wave * 32 + i * 8][0]);       \
        _Pragma("unroll") for (int i = 0; i < 6; ++i)                     \
            glds16(gb[i] + (koff), &Bs[buf][wave * 48 + i * 8][0]);       \
    } while (0)

    QKV_STAGE(0, 0);
    __syncthreads();                 // vmcnt(0) drain: buf0 ready

    int cur = 0;
    for (int kb = 0; kb < 6; ++kb) {
        if (kb < 5) QKV_STAGE(cur ^ 1, (kb + 1) * 64);   // DMA under MFMA below

#pragma unroll
        for (int ks = 0; ks < 2; ++ks) {
            bf16x8 a[4], b[6];
            const int ps = ((ks * 4 + quad) ^ (l16 & 7)) * 8;  // swizzled slot
#pragma unroll
            for (int mi = 0; mi < 4; ++mi)
                a[mi] = *(const bf16x8*)&As[cur][mw + mi * 16 + l16][ps];
#pragma unroll
            for (int ni = 0; ni < 6; ++ni)
                b[ni] = *(const bf16x8*)&Bs[cur][nw + ni * 16 + l16][ps];
#pragma unroll
            for (int mi = 0; mi < 4; ++mi)
#pragma unroll
                for (int ni = 0; ni < 6; ++ni) acc[mi][ni] = mfma16(a[mi], b[ni], acc[mi][ni]);
        }
        if (kb < 5) {
            __syncthreads();         // drains next-tile DMA + guards buffer swap
            cur ^= 1;
        }
    }
#undef QKV_STAGE

    // epilogue: per ni, tensor = (nw+ni*16)>>6 is wave-uniform
    const int b = m0 >> 8, tbase = m0 & 255;
    unsigned short* qkbase[2] = {
        Qo + (size_t)((b * Hn + h) * Tn) * Dn,
        Ko + (size_t)((b * Hn + h) * Tn) * Dn };
    unsigned short* vdst = Vt + (size_t)((b * Hn + h) * Dn) * Tn;
#pragma unroll
    for (int ni = 0; ni < 6; ++ni) {
        const int ng = nw + ni * 16;
        const int tensor = ng >> 6;
        const int d = (ng & 63) + l16;
        if (tensor < 2) {
            unsigned short* dst = qkbase[tensor];
#pragma unroll
            for (int mi = 0; mi < 4; ++mi)
#pragma unroll
                for (int r = 0; r < 4; ++r) {
                    int t = tbase + mw + mi * 16 + quad * 4 + r;
                    dst[t * Dn + d] = f2bf(acc[mi][ni][r]);
                }
        } else {
#pragma unroll
            for (int mi = 0; mi < 4; ++mi) {
                int t0 = tbase + mw + mi * 16 + quad * 4;
                ushort4 pk;
                pk.x = f2bf(acc[mi][ni][0]);
                pk.y = f2bf(acc[mi][ni][1]);
                pk.z = f2bf(acc[mi][ni][2]);
                pk.w = f2bf(acc[mi][ni][3]);
                *(ushort4*)&vdst[d * Tn + t0] = pk;
            }
        }
    }
}

// ---------------------------------------------------------------- attention (flash-style)
// grid (H, B): one block per (b,h). 4 waves, 256 threads.
// K[256][64] and V^T[64][256] staged in LDS once (XOR-swizzled), then
// barrier-free: wave w handles q-row-16-groups {w, 7-w, 8+w, 15-w}
// (each wave does exactly 10 kt-iterations -> balanced causal work).
__global__ __launch_bounds__(256) void attn_kernel(
    const unsigned short* __restrict__ Q, const unsigned short* __restrict__ K,
    const unsigned short* __restrict__ Vt, unsigned short* __restrict__ attout) {
    __shared__ unsigned short Kt[256][64];     // 32 KB, slot ^= (t&7)
    __shared__ unsigned short Vl[64][256];     // 32 KB, slot ^= (d&7)
    __shared__ unsigned short P[4][16][72];    // 9 KB, per-wave P / O staging

    const int h = blockIdx.x, b = blockIdx.y;
    const unsigned short* Qb = Q + (size_t)((b * Hn + h) * Tn) * Dn;
    const unsigned short* Kb = K + (size_t)((b * Hn + h) * Tn) * Dn;
    const unsigned short* Vb = Vt + (size_t)((b * Hn + h) * Dn) * Tn;

    const int tid = threadIdx.x;
    const int wave = tid >> 6, lane = tid & 63;
    const int quad = lane >> 4, l16 = lane & 15;

    // ---- stage K (32 chunks of 8 rows x 64) and V (32 chunks of 2 rows x 256)
    {
        // K: lane l -> row 8c+(l>>3), physical slot l&7; source slot (l&7)^(t&7)
        const unsigned short* kg = Kb + (size_t)(lane >> 3) * Dn + ((lane & 7) ^ (lane >> 3)) * 8;
#pragma unroll
        for (int i = 0; i < 8; ++i) {
            const int c = wave * 8 + i;
            glds16(kg + (size_t)c * 8 * Dn, &Kt[c * 8][0]);
        }
        // V: lane l -> row 2c+(l>>5), physical slot l&31; source slot (l&31)^(d&7)
#pragma unroll
        for (int i = 0; i < 8; ++i) {
            const int c = wave * 8 + i;
            const int d = c * 2 + (lane >> 5);
            const int j = (lane & 31) ^ (d & 7);
            glds16(Vb + (size_t)d * Tn + j * 8, &Vl[c * 2][0]);
        }
    }
    __syncthreads();   // only barrier: K/V resident for the whole block

    const float cexp = 0.125f * 1.44269504f;   // scale * log2(e)
    const int grp[4] = {wave, 7 - wave, 8 + wave, 15 - wave};

    for (int gi = 0; gi < 4; ++gi) {
        const int g = grp[gi];
        const int q0 = g * 16;

        bf16x8 aq[2];
#pragma unroll
        for (int ks = 0; ks < 2; ++ks)
            aq[ks] = *(const bf16x8*)&Qb[(q0 + l16) * Dn + ks * 32 + quad * 8];

        f32x4 O[4];
#pragma unroll
        for (int i = 0; i < 4; ++i) O[i] = (f32x4){0.f, 0.f, 0.f, 0.f};
        float rsum[4] = {0.f, 0.f, 0.f, 0.f};

        const int ktmax = g >> 2;              // wave-uniform
        for (int kt = 0; kt <= ktmax; ++kt) {
            f32x4 S[4];
#pragma unroll
            for (int i = 0; i < 4; ++i) S[i] = (f32x4){0.f, 0.f, 0.f, 0.f};
#pragma unroll
            for (int ks = 0; ks < 2; ++ks)
#pragma unroll
                for (int ni = 0; ni < 4; ++ni) {
                    bf16x8 bk = *(const bf16x8*)
                        &Kt[kt * 64 + ni * 16 + l16][(((ks * 4 + quad) ^ (l16 & 7)) * 8)];
                    S[ni] = mfma16(aq[ks], bk, S[ni]);
                }

            // exp + row-sum + P (wave-local rows => no barrier)
#pragma unroll
            for (int ni = 0; ni < 4; ++ni)
#pragma unroll
                for (int r = 0; r < 4; ++r) {
                    int col = kt * 64 + ni * 16 + l16;
                    float p = exp2f(S[ni][r] * cexp);
                    p = (col > q0 + quad * 4 + r) ? 0.f : p;
                    rsum[r] += p;
                    P[wave][quad * 4 + r][ni * 16 + l16] = f2bf(p);
                }

#pragma unroll
            for (int ks = 0; ks < 2; ++ks) {
                bf16x8 ap = *(const bf16x8*)&P[wave][l16][ks * 32 + quad * 8];
#pragma unroll
                for (int ni = 0; ni < 4; ++ni) {
                    bf16x8 bv = *(const bf16x8*)
                        &Vl[ni * 16 + l16][(((kt * 8 + ks * 4 + quad) ^ (l16 & 7)) * 8)];
                    O[ni] = mfma16(ap, bv, O[ni]);
                }
            }
        }

        // reduce row sums across the 16 lanes holding each row
#pragma unroll
        for (int r = 0; r < 4; ++r) {
            float s = rsum[r];
            s += __shfl_xor(s, 1);
            s += __shfl_xor(s, 2);
            s += __shfl_xor(s, 4);
            s += __shfl_xor(s, 8);
            rsum[r] = s;
        }

        // stage O in P[wave], then coalesced 16B stores (wave-local, no barrier)
#pragma unroll
        for (int r = 0; r < 4; ++r) {
            float inv = 1.0f / rsum[r];
#pragma unroll
            for (int ni = 0; ni < 4; ++ni)
                P[wave][quad * 4 + r][ni * 16 + l16] = f2bf(O[ni][r] * inv);
        }
        const int row = lane >> 2;             // 0..15
        const int colc = (lane & 3) * 16;      // 0,16,32,48
        unsigned short* dst = attout + (size_t)(b * Tn + q0 + row) * (Hn * Dn) + h * Dn + colc;
        *(uint4*)dst = *(const uint4*)&P[wave][row][colc];
        *(uint4*)(dst + 8) = *(const uint4*)&P[wave][row][colc + 8];
    }
}

// ---------------------------------------------------------------- output projection
// grid (3, 512): n-tile (fast, for attout L2 reuse) x m-tile. 128x128 tile,
// gl_lds double-buffered 2-phase, same swizzle as qkv.
__global__ __launch_bounds__(256) void proj_gemm(
    const unsigned short* __restrict__ attout, const unsigned short* __restrict__ wpt,
    const float* __restrict__ bproj, float* __restrict__ out) {
    __shared__ unsigned short As[2][128][64];   // 32 KB
    __shared__ unsigned short Bs[2][128][64];   // 32 KB (64 KB total -> 2 blk/CU)

    const int n0 = blockIdx.x * 128;
    const int m0 = blockIdx.y * 128;

    const int tid = threadIdx.x;
    const int wave = tid >> 6, lane = tid & 63;
    const int quad = lane >> 4, l16 = lane & 15;
    const int mw = (wave >> 1) * 64, nw = (wave & 1) * 64;

    f32x4 acc[4][4];
#pragma unroll
    for (int i = 0; i < 4; ++i)
#pragma unroll
        for (int j = 0; j < 4; ++j) acc[i][j] = (f32x4){0.f, 0.f, 0.f, 0.f};

    const int lr = lane >> 3;
    const int js = (lane & 7) ^ lr;

    const unsigned short* ga[4];
    const unsigned short* gb[4];
#pragma unroll
    for (int i = 0; i < 4; ++i) {
        ga[i] = attout + (size_t)(m0 + wave * 32 + i * 8 + lr) * En + js * 8;
        gb[i] = wpt + (size_t)(n0 + wave * 32 + i * 8 + lr) * En + js * 8;
    }

#define PROJ_STAGE(buf, koff)                                             \
    do {                                                                  \
        _Pragma("unroll") for (int i = 0; i < 4; ++i)                     \
            glds16(ga[i] + (koff), &As[buf][wave * 32 + i * 8][0]);       \
        _Pragma("unroll") for (int i = 0; i < 4; ++i)                     \
            glds16(gb[i] + (koff), &Bs[buf][wave * 32 + i * 8][0]);       \
    } while (0)

    PROJ_STAGE(0, 0);
    __syncthreads();

    int cur = 0;
    for (int kb = 0; kb < 6; ++kb) {
        if (kb < 5) PROJ_STAGE(cur ^ 1, (kb + 1) * 64);

#pragma unroll
        for (int ks = 0; ks < 2; ++ks) {
            bf16x8 a[4], bb[4];
            const int ps = ((ks * 4 + quad) ^ (l16 & 7)) * 8;
#pragma unroll
            for (int mi = 0; mi < 4; ++mi)
                a[mi] = *(const bf16x8*)&As[cur][mw + mi * 16 + l16][ps];
#pragma unroll
            for (int ni = 0; ni < 4; ++ni)
                bb[ni] = *(const bf16x8*)&Bs[cur][nw + ni * 16 + l16][ps];
#pragma unroll
            for (int mi = 0; mi < 4; ++mi)
#pragma unroll
                for (int ni = 0; ni < 4; ++ni) acc[mi][ni] = mfma16(a[mi], bb[ni], acc[mi][ni]);
        }
        if (kb < 5) {
            __syncthreads();
            cur ^= 1;
        }
    }
#undef PROJ_STAGE

#pragma unroll
    for (int mi = 0; mi < 4; ++mi)
#pragma unroll
        for (int ni = 0; ni < 4; ++ni)
#pragma unroll
            for (int r = 0; r < 4; ++r) {
                int row = m0 + mw + mi * 16 + quad * 4 + r;
                int col = n0 + nw + ni * 16 + l16;
                out[(size_t)row * En + col] = acc[mi][ni][r] + bproj[col];
            }
}

// ---------------------------------------------------------------- launch
extern "C" void kernel_launch(void* const* d_in, const int* in_sizes, int n_in,
                              void* d_out, int out_size, void* d_ws, size_t ws_size,
                              hipStream_t stream) {
    const float* x  = (const float*)d_in[0];
    const float* wq = (const float*)d_in[1];
    const float* wk = (const float*)d_in[2];
    const float* wv = (const float*)d_in[3];
    const float* wp = (const float*)d_in[4];
    const float* bp = (const float*)d_in[5];
    float* out = (float*)d_out;

    char* ws = (char*)d_ws;
    const size_t WT_OFF  = 0;                                  // 884736
    const size_t WPT_OFF = WT_OFF + 884736;                    // 294912
    const size_t Q_OFF   = WPT_OFF + 294912;                   // 50331648 each below
    const size_t K_OFF   = Q_OFF + 50331648ull;
    const size_t VT_OFF  = K_OFF + 50331648ull;
    const size_t XB_OFF  = VT_OFF + 50331648ull;               // xb; attout aliases this

    unsigned short* wt   = (unsigned short*)(ws + WT_OFF);
    unsigned short* wpt  = (unsigned short*)(ws + WPT_OFF);
    unsigned short* Qd   = (unsigned short*)(ws + Q_OFF);
    unsigned short* Kd   = (unsigned short*)(ws + K_OFF);
    unsigned short* Vtd  = (unsigned short*)(ws + VT_OFF);
    unsigned short* xbd  = (unsigned short*)(ws + XB_OFF);
    unsigned short* ao   = xbd;   // xb dead after qkv_gemm; attn overwrites it

    prep_kernel<<<2304, 256, 0, stream>>>(wq, wk, wv, wp, wt, wpt);
    xcast_kernel<<<12288, 256, 0, stream>>>(x, xbd);
    qkv_gemm<<<dim3(Hn, 512), 256, 0, stream>>>(xbd, wt, Qd, Kd, Vtd);
    attn_kernel<<<dim3(Hn, Bn), 256, 0, stream>>>(Qd, Kd, Vtd, ao);
    proj_gemm<<<dim3(3, 512), 256, 0, stream>>>(ao, wpt, bp, out);
}